// Round 2
// baseline (1126.951 us; speedup 1.0000x reference)
//
#include <hip/hip_runtime.h>

// Problem constants (from reference): F=4, B=16384, L=12, V=1e6, E=64
#define NF 4
#define NB 16384
#define NL 12
#define NV 1000000
#define NE 64

// One block = one batch element b. 4 waves = 4 features.
// Within a wave: lanes are split into 4 groups of 16; group g handles table
// row l = 4*i + g at iteration i, each lane loading a float4 (16B) of the row.
// One global_load_dwordx4 per wave therefore gathers FOUR table rows (1 KiB).
__global__ __launch_bounds__(256) void bag_kernel(
    const float* __restrict__ tables,      // [F, V, E]
    const float* __restrict__ pos_weights, // [F, L]
    const int*   __restrict__ indices,     // [F, B, L]
    const int*   __restrict__ lengths,     // [F, B]
    float*       __restrict__ pred,        // [B, F*E]  (d_out + 1)
    float*       __restrict__ partial)     // [NB] block partial sums for loss
{
    const int tid  = threadIdx.x;
    const int lane = tid & 63;
    const int f    = tid >> 6;       // wave id == feature id
    const int b    = blockIdx.x;

    const int len = lengths[f * NB + b];
    const int nn  = len < NL ? len : NL;

    const int*    idxp = indices + ((size_t)f * NB + b) * NL;
    const float*  pw   = pos_weights + f * NL;
    const float4* tbl  = (const float4*)(tables + (size_t)f * (size_t)NV * NE);

    // Lanes 0..11 load the 12 indices / position weights in parallel.
    int   idx_l = 0;
    float w_l   = 0.0f;
    if (lane < NL) {
        idx_l = idxp[lane];
        w_l   = (lane < nn) ? pw[lane] : 0.0f;
    }

    const int g = lane >> 4;   // row group within wave (0..3)
    const int j = lane & 15;   // float4 column within row (0..15)

    float ax = 0.0f, ay = 0.0f, az = 0.0f, aw = 0.0f;

#pragma unroll
    for (int i = 0; i < 3; ++i) {
        const int l = 4 * i + g;                 // row position this lane covers
        const int   my_idx = __shfl(idx_l, l, 64);
        const float my_w   = __shfl(w_l,   l, 64);
        if (l < nn) {
            const float4 v = tbl[(size_t)my_idx * (NE / 4) + j];
            ax += my_w * v.x;
            ay += my_w * v.y;
            az += my_w * v.z;
            aw += my_w * v.w;
        }
    }

    // Sum the 4 row-groups: after xor-16 and xor-32, every lane holds the
    // pooled value for its column j.
    ax += __shfl_xor(ax, 16, 64); ax += __shfl_xor(ax, 32, 64);
    ay += __shfl_xor(ay, 16, 64); ay += __shfl_xor(ay, 32, 64);
    az += __shfl_xor(az, 16, 64); az += __shfl_xor(az, 32, 64);
    aw += __shfl_xor(aw, 16, 64); aw += __shfl_xor(aw, 32, 64);

    // Lanes 0..15 write the pooled row: 256B contiguous per (b,f).
    if (lane < 16) {
        float4 outv = {ax, ay, az, aw};
        ((float4*)pred)[((size_t)b * NF + f) * (NE / 4) + j] = outv;
    }

    // --- deterministic partial sum for the loss ---
    // Every lane holds the pooled value for column j = lane&15 (4 copies).
    float s = (ax + ay) + (az + aw);
    // Reduce over j (bits 0..3): every lane ends with sum over 16 columns.
    s += __shfl_xor(s, 1, 64);
    s += __shfl_xor(s, 2, 64);
    s += __shfl_xor(s, 4, 64);
    s += __shfl_xor(s, 8, 64);

    __shared__ float wsum[4];
    if (lane == 0) wsum[f] = s;
    __syncthreads();
    if (tid == 0)
        partial[b] = (wsum[0] + wsum[1]) + (wsum[2] + wsum[3]);
}

// Single-block deterministic reduce of the 16384 partials -> loss.
__global__ __launch_bounds__(256) void loss_kernel(
    const float* __restrict__ partial,
    float*       __restrict__ loss_out)
{
    const int tid  = threadIdx.x;
    const int lane = tid & 63;
    const int wv   = tid >> 6;

    float s = 0.0f;
    for (int i = tid; i < NB; i += 256)
        s += partial[i];

#pragma unroll
    for (int off = 32; off > 0; off >>= 1)
        s += __shfl_down(s, off, 64);

    __shared__ float wsum[4];
    if (lane == 0) wsum[wv] = s;
    __syncthreads();
    if (tid == 0) {
        const double denom = (double)NB * (double)NF * (double)NE;
        loss_out[0] = (float)(((double)wsum[0] + wsum[1] + wsum[2] + wsum[3]) / denom);
    }
}

extern "C" void kernel_launch(void* const* d_in, const int* in_sizes, int n_in,
                              void* d_out, int out_size, void* d_ws, size_t ws_size,
                              hipStream_t stream) {
    const float* tables      = (const float*)d_in[0];
    const float* pos_weights = (const float*)d_in[1];
    const int*   indices     = (const int*)d_in[2];
    const int*   lengths     = (const int*)d_in[3];

    float* out     = (float*)d_out;     // out[0] = loss, out[1..] = pred [B, F*E]
    float* pred    = out + 1;
    float* partial = (float*)d_ws;      // NB floats = 64 KiB

    bag_kernel<<<NB, 256, 0, stream>>>(tables, pos_weights, indices, lengths, pred, partial);
    loss_kernel<<<1, 256, 0, stream>>>(partial, out);
}